// Round 9
// baseline (195.183 us; speedup 1.0000x reference)
//
#include <hip/hip_runtime.h>

// Problem constants (fixed by setup_inputs)
#define Bsz 512
#define Tsz 12
#define Dsz 1024
#define Osz 512
#define Mrows (Bsz * Tsz)          // 6144 flattened rows
#define LIN_ELEMS (Mrows * Osz)    // 3145728
#define LIN_BYTES ((size_t)LIN_ELEMS * 4)

// ---------------- K1: SGEMM 6144x512x1024, 128x128 tile, BK=16, 128 thr, 8x16/thread ----
// R8 diagnosis: 53-57% VALUBusy == LDS-instruction-throughput bound (336 LDS-pipe cyc vs
// 192 VALU cyc per kk at 6x8/8x8 tiles). 8x16 tile: 6 b128 reads per 128 FMAs = 0.56
// LDS-cyc/FMA -> near-balanced. k-major tiles, immediate-offset reads, stride 132
// (reads <=2-way; transpose writes 2-way: 16*c4 mod 32 has only 2 values for c4 in 0..3).
#define BK 16
#define NTH1 128
#define STR 132                      // tile row stride in floats (mod 32 = 4, mod 4 = 0)
#define HALF_F (BK * STR)            // 2112 floats per matrix per buffer
#define TILE_F (2 * HALF_F)          // 4224 floats (A + W); x2 dbuf = 33792 B

__global__ __launch_bounds__(NTH1) void gemm_tile(
    const float* __restrict__ x,     // (6144, 1024)
    const float* __restrict__ Wm,    // (512, 1024)
    float* __restrict__ lin,         // ws: (splitk, 6144, 512)
    int nk)                          // K-steps (of BK=16) per split
{
    __shared__ __align__(16) float smem[2 * TILE_F];
    const int tid = threadIdx.x;
    const int ty  = tid >> 3;    // 0..15 -> rows ty*8 .. ty*8+7
    const int tx  = tid & 7;     // 0..7  -> cols tx*16 .. tx*16+15

    const int m0 = blockIdx.x * 128;
    const int n0 = blockIdx.y * 128;
    const int kbase = blockIdx.z * nk * BK;
    float* dst = lin + (size_t)blockIdx.z * LIN_ELEMS;

    const float* Ab = x  + (size_t)m0 * Dsz + kbase;
    const float* Wb = Wm + (size_t)n0 * Dsz + kbase;

    // staging: 128 rows x 4 quads = 512 quads each for A and W -> 4/thread each
    // (identical index pattern for A and W)
    int gS[4], sS[4];
#pragma unroll
    for (int i = 0; i < 4; ++i) {
        int f = tid + NTH1 * i;
        int row = f >> 2, c4 = f & 3;
        gS[i] = row * Dsz + c4 * 4;
        sS[i] = (c4 * 4) * STR + row;    // k-major: T[k][row], scalar scatter x4
    }

    float acc[8][16];
#pragma unroll
    for (int i = 0; i < 8; ++i)
#pragma unroll
        for (int j = 0; j < 16; ++j) acc[i][j] = 0.0f;

    // prologue: stage K-step 0 into buffer 0
    {
        float4 ra[4], rw[4];
#pragma unroll
        for (int i = 0; i < 4; ++i) ra[i] = *reinterpret_cast<const float4*>(Ab + gS[i]);
#pragma unroll
        for (int i = 0; i < 4; ++i) rw[i] = *reinterpret_cast<const float4*>(Wb + gS[i]);
#pragma unroll
        for (int i = 0; i < 4; ++i) {
            float* pa = smem + sS[i];
            pa[0] = ra[i].x; pa[STR] = ra[i].y; pa[2 * STR] = ra[i].z; pa[3 * STR] = ra[i].w;
            float* pw = smem + HALF_F + sS[i];
            pw[0] = rw[i].x; pw[STR] = rw[i].y; pw[2 * STR] = rw[i].z; pw[3 * STR] = rw[i].w;
        }
    }
    __syncthreads();

    int cur = 0;
    for (int k0i = 0; k0i < nk; ++k0i) {
        float4 ra[4], rw[4];
        const bool more = (k0i < nk - 1);
        if (more) {
            const int k0n = (k0i + 1) * BK;
#pragma unroll
            for (int i = 0; i < 4; ++i) ra[i] = *reinterpret_cast<const float4*>(Ab + gS[i] + k0n);
#pragma unroll
            for (int i = 0; i < 4; ++i) rw[i] = *reinterpret_cast<const float4*>(Wb + gS[i] + k0n);
        }

        // compute on buffer cur: 6 x ds_read_b128 + 128 FMA per kk, immediate offsets
        const float* As = smem + cur * TILE_F + ty * 8;
        const float* Ws = smem + cur * TILE_F + HALF_F + tx * 16;
#pragma unroll 4
        for (int kk = 0; kk < BK; ++kk) {
            float4 a0 = *reinterpret_cast<const float4*>(As + kk * STR);
            float4 a1 = *reinterpret_cast<const float4*>(As + kk * STR + 4);
            float4 w0 = *reinterpret_cast<const float4*>(Ws + kk * STR);
            float4 w1 = *reinterpret_cast<const float4*>(Ws + kk * STR + 4);
            float4 w2 = *reinterpret_cast<const float4*>(Ws + kk * STR + 8);
            float4 w3 = *reinterpret_cast<const float4*>(Ws + kk * STR + 12);
            float av[8] = {a0.x, a0.y, a0.z, a0.w, a1.x, a1.y, a1.z, a1.w};
            float wv[16] = {w0.x, w0.y, w0.z, w0.w, w1.x, w1.y, w1.z, w1.w,
                            w2.x, w2.y, w2.z, w2.w, w3.x, w3.y, w3.z, w3.w};
#pragma unroll
            for (int i = 0; i < 8; ++i)
#pragma unroll
                for (int j = 0; j < 16; ++j)
                    acc[i][j] = fmaf(av[i], wv[j], acc[i][j]);
        }

        if (more) {
            float* nt = smem + (cur ^ 1) * TILE_F;
#pragma unroll
            for (int i = 0; i < 4; ++i) {
                float* pa = nt + sS[i];
                pa[0] = ra[i].x; pa[STR] = ra[i].y; pa[2 * STR] = ra[i].z; pa[3 * STR] = ra[i].w;
                float* pw = nt + HALF_F + sS[i];
                pw[0] = rw[i].x; pw[STR] = rw[i].y; pw[2 * STR] = rw[i].z; pw[3 * STR] = rw[i].w;
            }
            __syncthreads();
            cur ^= 1;
        }
    }

    // epilogue: straight to global
#pragma unroll
    for (int i = 0; i < 8; ++i) {
        const int row = m0 + ty * 8 + i;
        float* p = dst + (size_t)row * Osz + n0 + tx * 16;
#pragma unroll
        for (int q = 0; q < 4; ++q) {
            float4 o;
            o.x = acc[i][q * 4]; o.y = acc[i][q * 4 + 1];
            o.z = acc[i][q * 4 + 2]; o.w = acc[i][q * 4 + 3];
            *reinterpret_cast<float4*>(p + q * 4) = o;
        }
    }
}

// ---------------- K2: dynamics + margin flag + exact fp64 fix ----------------
// MARGIN: realistic fp32 lin error ~3e-6 (incl. 1.25x recurrence gain); 30x headroom.
// All split partials loaded as INDEPENDENT float2s first (R8-proven ILP fix).
#define MARGIN 1e-4f

template <int NSPLIT>
__global__ __launch_bounds__(256) void dyn_fix(
    const float* __restrict__ lin,   // ws: (NSPLIT, 6144, 512)
    const float* __restrict__ x,     // (512, 12, 1024)
    const float* __restrict__ Wm,    // (512, 1024)
    const float* __restrict__ bias,  // (512)
    float* __restrict__ out)         // (512, 512)
{
    __shared__ __align__(16) float xs[Tsz * Dsz];   // 48 KB: this batch's x rows
    __shared__ int list[Osz];
    __shared__ int cnt;

    const int b   = blockIdx.x;
    const int tid = threadIdx.x;
    if (tid == 0) cnt = 0;
    __syncthreads();

    const int o = tid * 2;   // this thread owns outputs o, o+1
    {
        float2 part[Tsz][NSPLIT];
#pragma unroll
        for (int t = 0; t < Tsz; ++t)
#pragma unroll
            for (int s = 0; s < NSPLIT; ++s)
                part[t][s] = *reinterpret_cast<const float2*>(
                    lin + (size_t)s * LIN_ELEMS + (size_t)(b * Tsz + t) * Osz + o);

        const float2 bv = *reinterpret_cast<const float2*>(bias + o);
        float lax[Tsz], lay[Tsz];
#pragma unroll
        for (int t = 0; t < Tsz; ++t) {
            float sx = bv.x, sy = bv.y;
#pragma unroll
            for (int s = 0; s < NSPLIT; ++s) { sx += part[t][s].x; sy += part[t][s].y; }
            lax[t] = sx; lay[t] = sy;
        }

        // two independent dynamics chains (ILP)
        float vx = 0.0f, sxx = 0.0f, mx = 1e30f, cfx = 0.0f;
        float vy = 0.0f, syy = 0.0f, my = 1e30f, cfy = 0.0f;
        for (int oi = 0; oi < Tsz; ++oi) {
            float cx = 0.0f, cy = 0.0f;
#pragma unroll
            for (int t = 0; t < Tsz; ++t) {
                vx = vx * 0.2f * (1.0f - sxx) + lax[t];
                vy = vy * 0.2f * (1.0f - syy) + lay[t];
                mx = fminf(mx, fabsf(vx - 0.5f));
                my = fminf(my, fabsf(vy - 0.5f));
                sxx = (vx > 0.5f) ? 1.0f : 0.0f;
                syy = (vy > 0.5f) ? 1.0f : 0.0f;
                cx += sxx; cy += syy;
            }
            cfx = cx; cfy = cy;
        }
        float2 o2; o2.x = cfx; o2.y = cfy;
        *reinterpret_cast<float2*>(out + (size_t)b * Osz + o) = o2;
        if (mx < MARGIN) { int sl = atomicAdd(&cnt, 1); list[sl] = o; }
        if (my < MARGIN) { int sl = atomicAdd(&cnt, 1); list[sl] = o + 1; }
    }
    __syncthreads();

    const int n = cnt;
    if (n == 0) return;

    // stage x[b] (12 x 1024) into LDS, coalesced
    const float* xb = x + (size_t)b * Tsz * Dsz;
    for (int i = tid; i < Tsz * Dsz / 4; i += 256)
        reinterpret_cast<float4*>(xs)[i] = reinterpret_cast<const float4*>(xb)[i];
    __syncthreads();

    // one wave per flagged pair: exact fp64 dot over k, then fp64 dynamics on lane 0
    const int wv = tid >> 6;
    const int l  = tid & 63;
    for (int fi = wv; fi < n; fi += 4) {
        const int oo = list[fi];
        const float* wr = Wm + (size_t)oo * Dsz + l * 16;
        double dot[Tsz];
#pragma unroll
        for (int t = 0; t < Tsz; ++t) dot[t] = 0.0;
#pragma unroll
        for (int c4 = 0; c4 < 4; ++c4) {
            float4 w4 = *reinterpret_cast<const float4*>(wr + c4 * 4);
            const double w0 = (double)w4.x, w1 = (double)w4.y,
                         w2 = (double)w4.z, w3 = (double)w4.w;
#pragma unroll
            for (int t = 0; t < Tsz; ++t) {
                float4 x4 = *reinterpret_cast<const float4*>(xs + t * Dsz + l * 16 + c4 * 4);
                double d = dot[t];
                d = fma((double)x4.x, w0, d);
                d = fma((double)x4.y, w1, d);
                d = fma((double)x4.z, w2, d);
                dot[t] = fma((double)x4.w, w3, d);
            }
        }
#pragma unroll
        for (int off = 32; off; off >>= 1)
#pragma unroll
            for (int t = 0; t < Tsz; ++t)
                dot[t] += __shfl_down(dot[t], off);
        if (l == 0) {
            const double bvd = (double)bias[oo];
            double v = 0.0, s = 0.0, c = 0.0;
            for (int oi = 0; oi < Tsz; ++oi) {
                c = 0.0;
#pragma unroll
                for (int t = 0; t < Tsz; ++t) {
                    v = v * 0.2 * (1.0 - s) + (dot[t] + bvd);
                    s = (v > 0.5) ? 1.0 : 0.0;
                    c += s;
                }
            }
            out[(size_t)b * Osz + oo] = (float)c;
        }
    }
}

// ---------------- Fallback: proven round-1 fused fp64 kernel (ws too small) ----------------
#define F_AST 100
#define F_WST 68
#define F_BUFST 65
#define F_ABYTES (32 * F_AST * 4)

__global__ __launch_bounds__(192) void snn_fused_fb(
    const float* __restrict__ x, const float* __restrict__ Wm,
    const float* __restrict__ bias, float* __restrict__ out)
{
    __shared__ __align__(16) char smem[96 * F_BUFST * 8];
    float*  AsT = reinterpret_cast<float*>(smem);
    float*  WsT = reinterpret_cast<float*>(smem + F_ABYTES);
    double* buf = reinterpret_cast<double*>(smem);

    const int tid = threadIdx.x;
    const int ty  = tid >> 4;
    const int tx  = tid & 15;
    const int n0 = blockIdx.x * 64;
    const int b0 = blockIdx.y * 8;
    const int r0 = b0 * Tsz;

    double acc[8][4];
#pragma unroll
    for (int i = 0; i < 8; ++i)
#pragma unroll
        for (int j = 0; j < 4; ++j) acc[i][j] = 0.0;

    const float* Abase = x  + (size_t)r0 * Dsz;
    const float* Wbase = Wm + (size_t)n0 * Dsz;

    for (int k0 = 0; k0 < Dsz; k0 += 32) {
        __syncthreads();
#pragma unroll
        for (int it = 0; it < 4; ++it) {
            int idx = tid + 192 * it;
            int row = idx >> 3, c4 = idx & 7;
            float4 v = *reinterpret_cast<const float4*>(Abase + (size_t)row * Dsz + k0 + c4 * 4);
            int kb = c4 * 4;
            AsT[(kb + 0) * F_AST + row] = v.x;
            AsT[(kb + 1) * F_AST + row] = v.y;
            AsT[(kb + 2) * F_AST + row] = v.z;
            AsT[(kb + 3) * F_AST + row] = v.w;
        }
#pragma unroll
        for (int it = 0; it < 3; ++it) {
            int idx = tid + 192 * it;
            if (idx < 512) {
                int row = idx >> 3, c4 = idx & 7;
                float4 v = *reinterpret_cast<const float4*>(Wbase + (size_t)row * Dsz + k0 + c4 * 4);
                int kb = c4 * 4;
                WsT[(kb + 0) * F_WST + row] = v.x;
                WsT[(kb + 1) * F_WST + row] = v.y;
                WsT[(kb + 2) * F_WST + row] = v.z;
                WsT[(kb + 3) * F_WST + row] = v.w;
            }
        }
        __syncthreads();
#pragma unroll 4
        for (int kk = 0; kk < 32; ++kk) {
            const float* ar = &AsT[kk * F_AST + ty * 8];
            float4 a0 = *reinterpret_cast<const float4*>(ar);
            float4 a1 = *reinterpret_cast<const float4*>(ar + 4);
            float4 w0 = *reinterpret_cast<const float4*>(&WsT[kk * F_WST + tx * 4]);
            double ad[8] = {(double)a0.x, (double)a0.y, (double)a0.z, (double)a0.w,
                            (double)a1.x, (double)a1.y, (double)a1.z, (double)a1.w};
            double wd[4] = {(double)w0.x, (double)w0.y, (double)w0.z, (double)w0.w};
#pragma unroll
            for (int i = 0; i < 8; ++i)
#pragma unroll
                for (int j = 0; j < 4; ++j)
                    acc[i][j] = fma(ad[i], wd[j], acc[i][j]);
        }
    }
    __syncthreads();
#pragma unroll
    for (int i = 0; i < 8; ++i)
#pragma unroll
        for (int j = 0; j < 4; ++j)
            buf[(ty * 8 + i) * F_BUFST + (tx * 4 + j)] = acc[i][j];
    __syncthreads();

    for (int idx = tid; idx < 512; idx += 192) {
        int bl = idx >> 6, ol = idx & 63;
        double bv = (double)bias[n0 + ol];
        double la[Tsz];
#pragma unroll
        for (int t = 0; t < Tsz; ++t)
            la[t] = buf[(bl * Tsz + t) * F_BUFST + ol] + bv;
        double v = 0.0, s = 0.0;
        float cnt = 0.0f;
        for (int oi = 0; oi < Tsz; ++oi) {
            double c = 0.0;
#pragma unroll
            for (int t = 0; t < Tsz; ++t) {
                v = v * 0.2 * (1.0 - s) + la[t];
                s = (v > 0.5) ? 1.0 : 0.0;
                c += s;
            }
            cnt = (float)c;
        }
        out[(size_t)(b0 + bl) * Osz + (n0 + ol)] = cnt;
    }
}

extern "C" void kernel_launch(void* const* d_in, const int* in_sizes, int n_in,
                              void* d_out, int out_size, void* d_ws, size_t ws_size,
                              hipStream_t stream) {
    const float* x    = (const float*)d_in[0];   // (512,12,1024) fp32
    const float* Wm   = (const float*)d_in[1];   // (512,1024) fp32
    const float* bias = (const float*)d_in[2];   // (512) fp32
    float* out = (float*)d_out;                  // (512,512) fp32

    if (ws_size >= 4 * LIN_BYTES) {
        float* lin = (float*)d_ws;
        dim3 g1(Mrows / 128, Osz / 128, 4);      // 48 x 4 x 4 = 768 blocks, all co-resident
        hipLaunchKernelGGL(gemm_tile, g1, dim3(NTH1), 0, stream, x, Wm, lin, 16);
        hipLaunchKernelGGL((dyn_fix<4>), dim3(Bsz), dim3(256), 0, stream,
                           lin, x, Wm, bias, out);
    } else if (ws_size >= 2 * LIN_BYTES) {
        float* lin = (float*)d_ws;
        dim3 g1(Mrows / 128, Osz / 128, 2);      // 384 blocks
        hipLaunchKernelGGL(gemm_tile, g1, dim3(NTH1), 0, stream, x, Wm, lin, 32);
        hipLaunchKernelGGL((dyn_fix<2>), dim3(Bsz), dim3(256), 0, stream,
                           lin, x, Wm, bias, out);
    } else if (ws_size >= LIN_BYTES) {
        float* lin = (float*)d_ws;
        dim3 g1(Mrows / 128, Osz / 128, 1);      // 192 blocks
        hipLaunchKernelGGL(gemm_tile, g1, dim3(NTH1), 0, stream, x, Wm, lin, 64);
        hipLaunchKernelGGL((dyn_fix<1>), dim3(Bsz), dim3(256), 0, stream,
                           lin, x, Wm, bias, out);
    } else {
        dim3 grid(Osz / 64, Bsz / 8);            // (8, 64)
        hipLaunchKernelGGL(snn_fused_fb, grid, dim3(192), 0, stream, x, Wm, bias, out);
    }
}

// Round 10
// 180.068 us; speedup vs baseline: 1.0839x; 1.0839x over previous
//
#include <hip/hip_runtime.h>

// Problem constants (fixed by setup_inputs)
#define Bsz 512
#define Tsz 12
#define Dsz 1024
#define Osz 512
#define Mrows (Bsz * Tsz)          // 6144 flattened rows
#define LIN_ELEMS (Mrows * Osz)    // 3145728
#define LIN_BYTES ((size_t)LIN_ELEMS * 4)
#define CNT_BYTES 2048             // 512 int counters
#define LIST_BYTES (512 * 512 * 4) // per-batch flag lists (worst case all o)
#define EXTRA_BYTES (CNT_BYTES + LIST_BYTES + 256)

// ---------------- K1: SGEMM 6144x512x1024, 192x128 tile, 256 thr, 12x8/thread ----
// R9 lesson: per-thread cols/rows must be CHUNKED (stride-64) so each b128's distinct
// addresses tile the banks: rows ty*4+{0,64,128}, cols tx*4+{0,64} -> all reads <=2-way
// (free, m136). Staging strides 196/132 (==4 mod 32) -> scatter writes 2-way.
// 5 b128 / 96 FMA-instr = best LDS-per-FMA of the feasible shapes.
#define BKg 16
#define NTHg 256
#define STRA 196                     // A tile row stride (192+4)
#define STRW 132                     // W tile row stride (128+4)
#define A_F (BKg * STRA)             // 3136 floats
#define W_F (BKg * STRW)             // 2112 floats
#define TILE_Fg (A_F + W_F)          // 5248 floats = 20992 B; x2 dbuf = 41984 B

__global__ __launch_bounds__(NTHg) void gemm_tile(
    const float* __restrict__ x,     // (6144, 1024)
    const float* __restrict__ Wm,    // (512, 1024)
    float* __restrict__ lin,         // ws: (splitk, 6144, 512)
    int nk)                          // K-steps (of BKg=16) per split
{
    __shared__ __align__(16) float smem[2 * TILE_Fg];
    const int tid = threadIdx.x;
    const int ty  = tid >> 4;    // 0..15 -> rows ty*4 + {0,64,128}
    const int tx  = tid & 15;    // 0..15 -> cols tx*4 + {0,64}

    const int m0 = blockIdx.x * 192;
    const int n0 = blockIdx.y * 128;
    const int kbase = blockIdx.z * nk * BKg;
    float* dst = lin + (size_t)blockIdx.z * LIN_ELEMS;

    const float* Ab = x  + (size_t)m0 * Dsz + kbase;
    const float* Wb = Wm + (size_t)n0 * Dsz + kbase;

    // staging: A 192x4=768 quads -> 3/thread; W 128x4=512 quads -> 2/thread
    int gA[3], sA[3], gW[2], sW[2];
#pragma unroll
    for (int i = 0; i < 3; ++i) {
        int f = tid + NTHg * i;
        int row = f >> 2, c4 = f & 3;
        gA[i] = row * Dsz + c4 * 4;
        sA[i] = (c4 * 4) * STRA + row;   // k-major: AsT[k][row]
    }
#pragma unroll
    for (int i = 0; i < 2; ++i) {
        int f = tid + NTHg * i;
        int col = f >> 2, c4 = f & 3;
        gW[i] = col * Dsz + c4 * 4;
        sW[i] = (c4 * 4) * STRW + col;   // k-major: WsT[k][col]
    }

    float acc[12][8];
#pragma unroll
    for (int i = 0; i < 12; ++i)
#pragma unroll
        for (int j = 0; j < 8; ++j) acc[i][j] = 0.0f;

    // prologue: stage K-step 0 into buffer 0
    {
        float4 ra[3], rw[2];
#pragma unroll
        for (int i = 0; i < 3; ++i) ra[i] = *reinterpret_cast<const float4*>(Ab + gA[i]);
#pragma unroll
        for (int i = 0; i < 2; ++i) rw[i] = *reinterpret_cast<const float4*>(Wb + gW[i]);
#pragma unroll
        for (int i = 0; i < 3; ++i) {
            float* pa = smem + sA[i];
            pa[0] = ra[i].x; pa[STRA] = ra[i].y; pa[2 * STRA] = ra[i].z; pa[3 * STRA] = ra[i].w;
        }
#pragma unroll
        for (int i = 0; i < 2; ++i) {
            float* pw = smem + A_F + sW[i];
            pw[0] = rw[i].x; pw[STRW] = rw[i].y; pw[2 * STRW] = rw[i].z; pw[3 * STRW] = rw[i].w;
        }
    }
    __syncthreads();

    int cur = 0;
    for (int k0i = 0; k0i < nk; ++k0i) {
        float4 ra[3], rw[2];
        const bool more = (k0i < nk - 1);
        if (more) {
            const int k0n = (k0i + 1) * BKg;
#pragma unroll
            for (int i = 0; i < 3; ++i) ra[i] = *reinterpret_cast<const float4*>(Ab + gA[i] + k0n);
#pragma unroll
            for (int i = 0; i < 2; ++i) rw[i] = *reinterpret_cast<const float4*>(Wb + gW[i] + k0n);
        }

        const float* As = smem + cur * TILE_Fg + ty * 4;
        const float* Ws = smem + cur * TILE_Fg + A_F + tx * 4;
#pragma unroll 8
        for (int kk = 0; kk < BKg; ++kk) {
            float4 a0 = *reinterpret_cast<const float4*>(As + kk * STRA);
            float4 a1 = *reinterpret_cast<const float4*>(As + kk * STRA + 64);
            float4 a2 = *reinterpret_cast<const float4*>(As + kk * STRA + 128);
            float4 w0 = *reinterpret_cast<const float4*>(Ws + kk * STRW);
            float4 w1 = *reinterpret_cast<const float4*>(Ws + kk * STRW + 64);
            float av[12] = {a0.x, a0.y, a0.z, a0.w, a1.x, a1.y, a1.z, a1.w,
                            a2.x, a2.y, a2.z, a2.w};
            float wv[8]  = {w0.x, w0.y, w0.z, w0.w, w1.x, w1.y, w1.z, w1.w};
#pragma unroll
            for (int i = 0; i < 12; ++i)
#pragma unroll
                for (int j = 0; j < 8; ++j)
                    acc[i][j] = fmaf(av[i], wv[j], acc[i][j]);
        }

        if (more) {
            float* nt = smem + (cur ^ 1) * TILE_Fg;
#pragma unroll
            for (int i = 0; i < 3; ++i) {
                float* pa = nt + sA[i];
                pa[0] = ra[i].x; pa[STRA] = ra[i].y; pa[2 * STRA] = ra[i].z; pa[3 * STRA] = ra[i].w;
            }
#pragma unroll
            for (int i = 0; i < 2; ++i) {
                float* pw = nt + A_F + sW[i];
                pw[0] = rw[i].x; pw[STRW] = rw[i].y; pw[2 * STRW] = rw[i].z; pw[3 * STRW] = rw[i].w;
            }
            __syncthreads();
            cur ^= 1;
        }
    }

    // epilogue: acc[i=chunk*4+r][j=cchunk*4+c] -> row m0+ty*4+r+64*chunk, col n0+tx*4+c+64*cchunk
#pragma unroll
    for (int ch = 0; ch < 3; ++ch)
#pragma unroll
        for (int r = 0; r < 4; ++r) {
            const int row = m0 + ty * 4 + r + 64 * ch;
            float* p = dst + (size_t)row * Osz + n0;
            float4 o0, o1;
            o0.x = acc[ch * 4 + r][0]; o0.y = acc[ch * 4 + r][1];
            o0.z = acc[ch * 4 + r][2]; o0.w = acc[ch * 4 + r][3];
            o1.x = acc[ch * 4 + r][4]; o1.y = acc[ch * 4 + r][5];
            o1.z = acc[ch * 4 + r][6]; o1.w = acc[ch * 4 + r][7];
            *reinterpret_cast<float4*>(p + tx * 4)      = o0;
            *reinterpret_cast<float4*>(p + 64 + tx * 4) = o1;
        }
}

// ---------------- K2: dynamics + margin flag (NO x-staging / fp64 here) ----------------
// MARGIN: worst-case fp32 lin error ~3.5e-5 x1.25 recurrence gain = 4.4e-5; 2.3x headroom.
#define MARGIN 1e-4f

template <int NSPLIT>
__global__ __launch_bounds__(256) void dyn_flag(
    const float* __restrict__ lin,   // ws: (NSPLIT, 6144, 512)
    const float* __restrict__ bias,  // (512)
    float* __restrict__ out,         // (512, 512)
    int* __restrict__ cnt,           // ws: (512) zeroed counters
    int* __restrict__ list)          // ws: (512, 512)
{
    const int b   = blockIdx.x;
    const int tid = threadIdx.x;
    const int o   = tid * 2;

    float2 part[Tsz][NSPLIT];
#pragma unroll
    for (int t = 0; t < Tsz; ++t)
#pragma unroll
        for (int s = 0; s < NSPLIT; ++s)
            part[t][s] = *reinterpret_cast<const float2*>(
                lin + (size_t)s * LIN_ELEMS + (size_t)(b * Tsz + t) * Osz + o);

    const float2 bv = *reinterpret_cast<const float2*>(bias + o);
    float lax[Tsz], lay[Tsz];
#pragma unroll
    for (int t = 0; t < Tsz; ++t) {
        float sx = bv.x, sy = bv.y;
#pragma unroll
        for (int s = 0; s < NSPLIT; ++s) { sx += part[t][s].x; sy += part[t][s].y; }
        lax[t] = sx; lay[t] = sy;
    }

    float vx = 0.0f, sxx = 0.0f, mx = 1e30f, cfx = 0.0f;
    float vy = 0.0f, syy = 0.0f, my = 1e30f, cfy = 0.0f;
    for (int oi = 0; oi < Tsz; ++oi) {
        float cx = 0.0f, cy = 0.0f;
#pragma unroll
        for (int t = 0; t < Tsz; ++t) {
            vx = vx * 0.2f * (1.0f - sxx) + lax[t];
            vy = vy * 0.2f * (1.0f - syy) + lay[t];
            mx = fminf(mx, fabsf(vx - 0.5f));
            my = fminf(my, fabsf(vy - 0.5f));
            sxx = (vx > 0.5f) ? 1.0f : 0.0f;
            syy = (vy > 0.5f) ? 1.0f : 0.0f;
            cx += sxx; cy += syy;
        }
        cfx = cx; cfy = cy;
    }
    float2 o2; o2.x = cfx; o2.y = cfy;
    *reinterpret_cast<float2*>(out + (size_t)b * Osz + o) = o2;
    if (mx < MARGIN) { int sl = atomicAdd(&cnt[b], 1); list[b * 512 + sl] = o; }
    if (my < MARGIN) { int sl = atomicAdd(&cnt[b], 1); list[b * 512 + sl] = o + 1; }
}

// ---------------- K3: exact fp64 recompute for flagged pairs (block per batch) -------
__global__ __launch_bounds__(256) void fix_k(
    const float* __restrict__ x,     // (512, 12, 1024)
    const float* __restrict__ Wm,    // (512, 1024)
    const float* __restrict__ bias,  // (512)
    const int* __restrict__ cnt,
    const int* __restrict__ list,
    float* __restrict__ out)
{
    __shared__ __align__(16) float xs[Tsz * Dsz];   // 48 KB
    const int b   = blockIdx.x;
    const int tid = threadIdx.x;
    const int n   = cnt[b];
    if (n == 0) return;                              // block-uniform

    const float* xb = x + (size_t)b * Tsz * Dsz;
    for (int i = tid; i < Tsz * Dsz / 4; i += 256)
        reinterpret_cast<float4*>(xs)[i] = reinterpret_cast<const float4*>(xb)[i];
    __syncthreads();

    const int wv = tid >> 6;
    const int l  = tid & 63;
    for (int fi = wv; fi < n; fi += 4) {
        const int oo = list[b * 512 + fi];
        const float* wr = Wm + (size_t)oo * Dsz + l * 16;
        double dot[Tsz];
#pragma unroll
        for (int t = 0; t < Tsz; ++t) dot[t] = 0.0;
#pragma unroll
        for (int c4 = 0; c4 < 4; ++c4) {
            float4 w4 = *reinterpret_cast<const float4*>(wr + c4 * 4);
            const double w0 = (double)w4.x, w1 = (double)w4.y,
                         w2 = (double)w4.z, w3 = (double)w4.w;
#pragma unroll
            for (int t = 0; t < Tsz; ++t) {
                float4 x4 = *reinterpret_cast<const float4*>(xs + t * Dsz + l * 16 + c4 * 4);
                double d = dot[t];
                d = fma((double)x4.x, w0, d);
                d = fma((double)x4.y, w1, d);
                d = fma((double)x4.z, w2, d);
                dot[t] = fma((double)x4.w, w3, d);
            }
        }
#pragma unroll
        for (int off = 32; off; off >>= 1)
#pragma unroll
            for (int t = 0; t < Tsz; ++t)
                dot[t] += __shfl_down(dot[t], off);
        if (l == 0) {
            const double bvd = (double)bias[oo];
            double v = 0.0, s = 0.0, c = 0.0;
            for (int oi = 0; oi < Tsz; ++oi) {
                c = 0.0;
#pragma unroll
                for (int t = 0; t < Tsz; ++t) {
                    v = v * 0.2 * (1.0 - s) + (dot[t] + bvd);
                    s = (v > 0.5) ? 1.0 : 0.0;
                    c += s;
                }
            }
            out[(size_t)b * Osz + oo] = (float)c;
        }
    }
}

// ---------------- Fallback: proven round-1 fused fp64 kernel (ws too small) ----------------
#define F_AST 100
#define F_WST 68
#define F_BUFST 65
#define F_ABYTES (32 * F_AST * 4)

__global__ __launch_bounds__(192) void snn_fused_fb(
    const float* __restrict__ x, const float* __restrict__ Wm,
    const float* __restrict__ bias, float* __restrict__ out)
{
    __shared__ __align__(16) char smem[96 * F_BUFST * 8];
    float*  AsT = reinterpret_cast<float*>(smem);
    float*  WsT = reinterpret_cast<float*>(smem + F_ABYTES);
    double* buf = reinterpret_cast<double*>(smem);

    const int tid = threadIdx.x;
    const int ty  = tid >> 4;
    const int tx  = tid & 15;
    const int n0 = blockIdx.x * 64;
    const int b0 = blockIdx.y * 8;
    const int r0 = b0 * Tsz;

    double acc[8][4];
#pragma unroll
    for (int i = 0; i < 8; ++i)
#pragma unroll
        for (int j = 0; j < 4; ++j) acc[i][j] = 0.0;

    const float* Abase = x  + (size_t)r0 * Dsz;
    const float* Wbase = Wm + (size_t)n0 * Dsz;

    for (int k0 = 0; k0 < Dsz; k0 += 32) {
        __syncthreads();
#pragma unroll
        for (int it = 0; it < 4; ++it) {
            int idx = tid + 192 * it;
            int row = idx >> 3, c4 = idx & 7;
            float4 v = *reinterpret_cast<const float4*>(Abase + (size_t)row * Dsz + k0 + c4 * 4);
            int kb = c4 * 4;
            AsT[(kb + 0) * F_AST + row] = v.x;
            AsT[(kb + 1) * F_AST + row] = v.y;
            AsT[(kb + 2) * F_AST + row] = v.z;
            AsT[(kb + 3) * F_AST + row] = v.w;
        }
#pragma unroll
        for (int it = 0; it < 3; ++it) {
            int idx = tid + 192 * it;
            if (idx < 512) {
                int row = idx >> 3, c4 = idx & 7;
                float4 v = *reinterpret_cast<const float4*>(Wbase + (size_t)row * Dsz + k0 + c4 * 4);
                int kb = c4 * 4;
                WsT[(kb + 0) * F_WST + row] = v.x;
                WsT[(kb + 1) * F_WST + row] = v.y;
                WsT[(kb + 2) * F_WST + row] = v.z;
                WsT[(kb + 3) * F_WST + row] = v.w;
            }
        }
        __syncthreads();
#pragma unroll 4
        for (int kk = 0; kk < 32; ++kk) {
            const float* ar = &AsT[kk * F_AST + ty * 8];
            float4 a0 = *reinterpret_cast<const float4*>(ar);
            float4 a1 = *reinterpret_cast<const float4*>(ar + 4);
            float4 w0 = *reinterpret_cast<const float4*>(&WsT[kk * F_WST + tx * 4]);
            double ad[8] = {(double)a0.x, (double)a0.y, (double)a0.z, (double)a0.w,
                            (double)a1.x, (double)a1.y, (double)a1.z, (double)a1.w};
            double wd[4] = {(double)w0.x, (double)w0.y, (double)w0.z, (double)w0.w};
#pragma unroll
            for (int i = 0; i < 8; ++i)
#pragma unroll
                for (int j = 0; j < 4; ++j)
                    acc[i][j] = fma(ad[i], wd[j], acc[i][j]);
        }
    }
    __syncthreads();
#pragma unroll
    for (int i = 0; i < 8; ++i)
#pragma unroll
        for (int j = 0; j < 4; ++j)
            buf[(ty * 8 + i) * F_BUFST + (tx * 4 + j)] = acc[i][j];
    __syncthreads();

    for (int idx = tid; idx < 512; idx += 192) {
        int bl = idx >> 6, ol = idx & 63;
        double bv = (double)bias[n0 + ol];
        double la[Tsz];
#pragma unroll
        for (int t = 0; t < Tsz; ++t)
            la[t] = buf[(bl * Tsz + t) * F_BUFST + ol] + bv;
        double v = 0.0, s = 0.0;
        float cnt = 0.0f;
        for (int oi = 0; oi < Tsz; ++oi) {
            double c = 0.0;
#pragma unroll
            for (int t = 0; t < Tsz; ++t) {
                v = v * 0.2 * (1.0 - s) + la[t];
                s = (v > 0.5) ? 1.0 : 0.0;
                c += s;
            }
            cnt = (float)c;
        }
        out[(size_t)(b0 + bl) * Osz + (n0 + ol)] = cnt;
    }
}

extern "C" void kernel_launch(void* const* d_in, const int* in_sizes, int n_in,
                              void* d_out, int out_size, void* d_ws, size_t ws_size,
                              hipStream_t stream) {
    const float* x    = (const float*)d_in[0];   // (512,12,1024) fp32
    const float* Wm   = (const float*)d_in[1];   // (512,1024) fp32
    const float* bias = (const float*)d_in[2];   // (512) fp32
    float* out = (float*)d_out;                  // (512,512) fp32

    int splitk = 0;
    if      (ws_size >= 4 * LIN_BYTES + EXTRA_BYTES) splitk = 4;
    else if (ws_size >= 2 * LIN_BYTES + EXTRA_BYTES) splitk = 2;
    else if (ws_size >= 1 * LIN_BYTES + EXTRA_BYTES) splitk = 1;

    if (splitk) {
        float* lin  = (float*)d_ws;
        char*  base = (char*)d_ws + (size_t)splitk * LIN_BYTES;
        int*   cnt  = (int*)base;
        int*   list = (int*)(base + CNT_BYTES);
        hipMemsetAsync(cnt, 0, CNT_BYTES, stream);
        dim3 g1(Mrows / 192, Osz / 128, splitk);   // (32, 4, splitk)
        hipLaunchKernelGGL(gemm_tile, g1, dim3(NTHg), 0, stream, x, Wm, lin, 64 / splitk);
        if (splitk == 4)
            hipLaunchKernelGGL((dyn_flag<4>), dim3(Bsz), dim3(256), 0, stream,
                               lin, bias, out, cnt, list);
        else if (splitk == 2)
            hipLaunchKernelGGL((dyn_flag<2>), dim3(Bsz), dim3(256), 0, stream,
                               lin, bias, out, cnt, list);
        else
            hipLaunchKernelGGL((dyn_flag<1>), dim3(Bsz), dim3(256), 0, stream,
                               lin, bias, out, cnt, list);
        hipLaunchKernelGGL(fix_k, dim3(Bsz), dim3(256), 0, stream,
                           x, Wm, bias, cnt, list, out);
    } else {
        dim3 grid(Osz / 64, Bsz / 8);              // (8, 64)
        hipLaunchKernelGGL(snn_fused_fb, grid, dim3(192), 0, stream, x, Wm, bias, out);
    }
}